// Round 3
// baseline (341.898 us; speedup 1.0000x reference)
//
#include <hip/hip_runtime.h>
#include <hip/hip_bf16.h>

#define NUSERS 100000
#define NITEMS 50000
#define NN (NUSERS + NITEMS)      // 150000
#define NE 4000000
#define DIM 64
#define BQ 4096
#define NBIN ((NN + 255) >> 8)    // 586 bins of 256 rows
#define BINCAP 9216               // fixed slots/bin; mean w/ pads 7851, sigma ~90
#define EPB2 8192                 // edges per block in pass A (8/thread @ 1024)

typedef unsigned short u16;
typedef unsigned int u32;
typedef float v2f __attribute__((ext_vector_type(2)));
typedef unsigned u32x2 __attribute__((ext_vector_type(2)));

__device__ __forceinline__ float bf2f(u16 u) {
    return __uint_as_float(((unsigned)u) << 16);
}
__device__ __forceinline__ u16 f2bf(float f) {
    unsigned x = __float_as_uint(f);
    return (u16)((x + 0x7FFFu + ((x >> 16) & 1u)) >> 16);   // RNE
}
// unpack uint4 (8 bf16) into 4 packed-f32 accumulates (v_pk_add_f32)
__device__ __forceinline__ void add8p(v2f* acc2, uint4 u) {
    acc2[0] += (v2f){__uint_as_float(u.x << 16), __uint_as_float(u.x & 0xffff0000u)};
    acc2[1] += (v2f){__uint_as_float(u.y << 16), __uint_as_float(u.y & 0xffff0000u)};
    acc2[2] += (v2f){__uint_as_float(u.z << 16), __uint_as_float(u.z & 0xffff0000u)};
    acc2[3] += (v2f){__uint_as_float(u.w << 16), __uint_as_float(u.w & 0xffff0000u)};
}
// 32-bit voffset + SGPR base load: offset = c*128 + dgoff, fits 25 bits
__device__ __forceinline__ uint4 ld_row(const char* __restrict__ base, int c, int dgoff) {
    u32 off = ((u32)c << 7) + (u32)dgoff;
    return *(const uint4*)(base + off);
}

// ---- cross-lane adds on the VALU pipe (no ds/lgkm chains) ----
#if __has_builtin(__builtin_amdgcn_update_dpp)
__device__ __forceinline__ float xadd8(float x) {
    int y = __builtin_amdgcn_update_dpp(0, __float_as_int(x), 0x128, 0xF, 0xF, true);
    return x + __int_as_float(y);
}
#else
__device__ __forceinline__ float xadd8(float x) { return x + __shfl_xor(x, 8, 64); }
#endif
#if __has_builtin(__builtin_amdgcn_permlane16_swap)
__device__ __forceinline__ float xadd16(float x) {
    u32x2 r = __builtin_amdgcn_permlane16_swap(__float_as_uint(x), __float_as_uint(x),
                                               false, false);
    return __uint_as_float(r.x) + __uint_as_float(r.y);
}
#else
__device__ __forceinline__ float xadd16(float x) { return x + __shfl_xor(x, 16, 64); }
#endif
#if __has_builtin(__builtin_amdgcn_permlane32_swap)
__device__ __forceinline__ float xadd32(float x) {
    u32x2 r = __builtin_amdgcn_permlane32_swap(__float_as_uint(x), __float_as_uint(x),
                                               false, false);
    return __uint_as_float(r.x) + __uint_as_float(r.y);
}
#else
__device__ __forceinline__ float xadd32(float x) { return x + __shfl_xor(x, 32, 64); }
#endif

// wave-wide reduction over the 8 edge slots (lane bits 3,4,5), pure VALU pipe
__device__ __forceinline__ void reduce_acc(v2f* acc2) {
#pragma unroll
    for (int j = 0; j < 4; ++j) { acc2[j].x = xadd8(acc2[j].x);  acc2[j].y = xadd8(acc2[j].y);  }
#pragma unroll
    for (int j = 0; j < 4; ++j) { acc2[j].x = xadd16(acc2[j].x); acc2[j].y = xadd16(acc2[j].y); }
#pragma unroll
    for (int j = 0; j < 4; ++j) { acc2[j].x = xadd32(acc2[j].x); acc2[j].y = xadd32(acc2[j].y); }
}

// ---------------- pipelined SpMM helpers ----------------
struct MetaS { int s; int n; int m; };

template<bool MASKED>
__device__ __forceinline__ MetaS ldmeta(const int2* __restrict__ meta2,
                                        const unsigned char* __restrict__ mask, int r) {
    MetaS t; t.s = 0; t.n = 0; t.m = 0;
    if (r < NN) {
        int2 v = meta2[r];
        t.s = v.x; t.n = v.y;
        t.m = MASKED ? (int)mask[r] : 1;
    }
    return t;
}

// load 8 col slots; slots beyond n8 (or fully-masked rows) -> sentinel row NN
__device__ __forceinline__ void ldcols(int* cg, const int* __restrict__ col_s,
                                       MetaS mt, int eslot) {
    int n8 = (mt.n + 7) & ~7;
    int lim = mt.m ? n8 : 0;
#pragma unroll
    for (int g = 0; g < 8; ++g) {
        int c = col_s[mt.s + (g << 3) + eslot];
        cg[g] = ((g << 3) < lim) ? c : NN;
    }
}

__device__ __forceinline__ void issue4(uint4* v, const char* __restrict__ base2,
                                       const int* cg, int lo) {
#pragma unroll
    for (int g = 0; g < 4; ++g)
        v[g] = *(const uint4*)(base2 + (((u32)cg[lo + g]) << 7));
}

__device__ __forceinline__ void consume_store(const uint4* v, int big, MetaS mt,
        const int* __restrict__ col_s, const char* __restrict__ base2,
        int eslot, int dg, u16* __restrict__ out, int r) {
    v2f acc2[4] = {(v2f)0.f, (v2f)0.f, (v2f)0.f, (v2f)0.f};
#pragma unroll
    for (int g = 0; g < 4; ++g) add8p(acc2, v[g]);
    if (big) {
#pragma unroll
        for (int g = 4; g < 8; ++g) add8p(acc2, v[g]);
    }
    int n8 = (mt.n + 7) & ~7;
    if (n8 > 64) {                        // safety net; not expected with this input
        for (int i = 64 + eslot; i < n8; i += 8) {
            int c = col_s[mt.s + i];
            uint4 u = *(const uint4*)(base2 + (((u32)c) << 7));
            add8p(acc2, u);
        }
    }
    reduce_acc(acc2);
    if (eslot == 0) {
        float sc = (mt.n > 0) ? (1.0f / (float)mt.n) : 0.0f;   // dis[r]^2
        v2f vs = {sc, sc};
        u32 p[4];
#pragma unroll
        for (int j = 0; j < 4; ++j) {
            v2f t = acc2[j] * vs;
            __hip_bfloat162 h = __float22bfloat162_rn(make_float2(t.x, t.y));
            p[j] = *(u32*)&h;
        }
        ((uint4*)out)[(size_t)r * 8 + dg] = make_uint4(p[0], p[1], p[2], p[3]);
    }
}

// ---------------- persistent 2-deep pipelined SpMM ----------------
// t_{k+1}[r] = (1/deg[r]) * sum_{c in N(r)} t_k[c]
// Each wave owns rows {w, w+nw, ...}. Modulo-2 schedule: per phase, issue
// gathers for row k+1 (cols ready), load cols for k+2 (meta ready), load meta
// for k+3, then consume row k. Every dependency has a full phase of slack.
template<bool MASKED>
__global__ void __launch_bounds__(256) k_spmm_p(
        const int2* __restrict__ meta2, const int* __restrict__ col_s,
        const u16* __restrict__ in, u16* __restrict__ out,
        const unsigned char* __restrict__ mask) {
    int lane = threadIdx.x & 63;
    int eslot = lane >> 3, dg = lane & 7;
    const char* base2 = (const char*)in + (dg << 4);
    const int nw = gridDim.x << 2;                    // total waves
    int r = ((blockIdx.x << 8) + threadIdx.x) >> 6;   // first row = wave id

    MetaS M0 = ldmeta<MASKED>(meta2, mask, r);
    MetaS M1 = ldmeta<MASKED>(meta2, mask, r + nw);
    MetaS M2 = ldmeta<MASKED>(meta2, mask, r + 2 * nw);
    int cgA[8], cgB[8];
    uint4 vA[8], vB[8];
    ldcols(cgA, col_s, M0, eslot);
    int bigA = M0.m & (M0.n > 32), bigB = 0;
    if (M0.m)  issue4(vA, base2, cgA, 0);
    if (bigA)  issue4(vA + 4, base2, cgA, 4);
    ldcols(cgB, col_s, M1, eslot);

    for (;;) {
        // ---- phase A: vB <- row r+nw, cgA <- cols r+2nw, consume vA (row r)
        bigB = M1.m & (M1.n > 32);
        if (M1.m) issue4(vB, base2, cgB, 0);
        if (bigB) issue4(vB + 4, base2, cgB, 4);
        ldcols(cgA, col_s, M2, eslot);
        MetaS M3 = ldmeta<MASKED>(meta2, mask, r + 3 * nw);
        if (M0.m) consume_store(vA, bigA, M0, col_s, base2, eslot, dg, out, r);
        r += nw; if (r >= NN) break;
        M0 = M1; M1 = M2; M2 = M3;
        // ---- phase B: vA <- row r+nw, cgB <- cols r+2nw, consume vB (row r)
        bigA = M1.m & (M1.n > 32);
        if (M1.m) issue4(vA, base2, cgA, 0);
        if (bigA) issue4(vA + 4, base2, cgA, 4);
        ldcols(cgB, col_s, M2, eslot);
        M3 = ldmeta<MASKED>(meta2, mask, r + 3 * nw);
        if (M0.m) consume_store(vB, bigB, M0, col_s, base2, eslot, dg, out, r);
        r += nw; if (r >= NN) break;
        M0 = M1; M1 = M2; M2 = M3;
    }
}

// ---------------- single-row rowsum core (used by k_spmm_out) ----------------
template<int G>
__device__ __forceinline__ void rowsum_fix(const int* __restrict__ col_s, int start,
                                           int eslot, const char* __restrict__ inb,
                                           int dgoff, v2f* acc2) {
    int cg[G];
#pragma unroll
    for (int g = 0; g < G; ++g) cg[g] = col_s[start + (g << 3) + eslot];
    uint4 v[G];
#pragma unroll
    for (int g = 0; g < G; ++g) v[g] = ld_row(inb, cg[g], dgoff);
#if __has_builtin(__builtin_amdgcn_sched_barrier)
    __builtin_amdgcn_sched_barrier(0);
#endif
#pragma unroll
    for (int g = 0; g < G; ++g) add8p(acc2, v[g]);
}

__device__ __forceinline__ void rowsum_core(int start, int n8,
                                            const int* __restrict__ col_s,
                                            const char* __restrict__ inb,
                                            int eslot, int dgoff, v2f* acc2) {
    switch (n8 >> 3) {
    case 0: break;
    case 1: rowsum_fix<1>(col_s, start, eslot, inb, dgoff, acc2); break;
    case 2: rowsum_fix<2>(col_s, start, eslot, inb, dgoff, acc2); break;
    case 3: rowsum_fix<3>(col_s, start, eslot, inb, dgoff, acc2); break;
    case 4: rowsum_fix<4>(col_s, start, eslot, inb, dgoff, acc2); break;
    case 5: rowsum_fix<5>(col_s, start, eslot, inb, dgoff, acc2); break;
    case 6: rowsum_fix<6>(col_s, start, eslot, inb, dgoff, acc2); break;
    case 7: rowsum_fix<7>(col_s, start, eslot, inb, dgoff, acc2); break;
    case 8: rowsum_fix<8>(col_s, start, eslot, inb, dgoff, acc2); break;
    default: {
        int i = eslot;
        int c0 = col_s[start + i];
        uint4 v0 = ld_row(inb, c0, dgoff);
        for (i += 8; i < n8; i += 8) {
            int c1 = col_s[start + i];
            uint4 v1 = ld_row(inb, c1, dgoff);
            add8p(acc2, v0);
            v0 = v1;
        }
        add8p(acc2, v0);
    }
    }
}

// ---------------- init: bin cursors, m2 mask, sentinel rows ----------------
__global__ void k_init(int* __restrict__ bin_cur, u32* __restrict__ m2w,
                       u16* __restrict__ ea, u16* __restrict__ eb) {
    int t = blockIdx.x * blockDim.x + threadIdx.x;
    if (t < NBIN) bin_cur[t] = t * BINCAP;
    if (t < 37504) m2w[t] = 0;                 // zero 150016 bytes of m2
    if (t < 32) {                              // zero sentinel row NN in both tables
        ((u32*)(ea + (size_t)NN * DIM))[t] = 0;
        ((u32*)(eb + (size_t)NN * DIM))[t] = 0;
    }
}

// ---------------- Pass A: block-local counting sort, coalesced flush -------
__global__ void __launch_bounds__(1024) k_binA2(
        const int* __restrict__ row, const int* __restrict__ col,
        int* __restrict__ bin_cur, u32* __restrict__ pairs, int E) {
    __shared__ u32 stage[EPB2];            // 32 KB
    __shared__ int hist[NBIN];
    __shared__ int base_l[NBIN];
    __shared__ int cbase[NBIN];
    __shared__ int lcur[NBIN];
    __shared__ int s[1024];
    int t = threadIdx.x;
    int base = blockIdx.x * EPB2;
    int lim = min(E - base, EPB2);

    if (t < NBIN) hist[t] = 0;
    __syncthreads();

    for (int i = t; i < lim; i += 1024)
        atomicAdd(&hist[row[base + i] >> 8], 1);
    __syncthreads();

    int v = (t < NBIN) ? hist[t] : 0;
    s[t] = v;
    __syncthreads();
    for (int off = 1; off < 1024; off <<= 1) {
        int x = (t >= off) ? s[t - off] : 0;
        __syncthreads();
        s[t] += x;
        __syncthreads();
    }
    if (t < NBIN) {
        int excl = s[t] - v;
        base_l[t] = excl;
        lcur[t] = excl;
        cbase[t] = (v > 0) ? atomicAdd(&bin_cur[t], v) : 0;
    }
    __syncthreads();

    for (int i = t; i < lim; i += 1024) {
        int r = row[base + i];
        int c = col[base + i];
        int pos = atomicAdd(&lcur[r >> 8], 1);
        stage[pos] = ((u32)(r & 255) << 24) | (u32)c;
    }
    __syncthreads();

    int wv = t >> 6;
    int lane = t & 63;
    for (int b = wv; b < NBIN; b += 16) {
        int h = hist[b];
        int lb = base_l[b];
        size_t gb = (size_t)cbase[b];
        for (int i = lane; i < h; i += 64)
            pairs[gb + i] = stage[lb + i];
    }
}

// ---------------- Pass B: per-bin row sort; derives rs/deg/meta2; pads to 8 ----
__global__ void __launch_bounds__(1024) k_binB(
        const u32* __restrict__ pairs, const int* __restrict__ bin_cur,
        int* __restrict__ col_s, int* __restrict__ rs, int* __restrict__ deg,
        int2* __restrict__ meta2) {
    __shared__ int cnt[256];
    __shared__ int pscan[256];
    __shared__ int cur[256];
    int b = blockIdx.x;
    int t = threadIdx.x;
    int base = b * BINCAP;
    int end = bin_cur[b];
    if (t < 256) cnt[t] = 0;
    __syncthreads();
    for (int i = base + t; i < end; i += 1024)
        atomicAdd(&cnt[pairs[i] >> 24], 1);
    __syncthreads();
    int v = (t < 256) ? cnt[t] : 0;
    int pv = (v + 7) & ~7;                    // row segment padded to multiple of 8
    if (t < 256) pscan[t] = pv;
    __syncthreads();
    for (int off = 1; off < 256; off <<= 1) {
        int x = (t >= off && t < 256) ? pscan[t - off] : 0;
        __syncthreads();
        if (t < 256) pscan[t] += x;
        __syncthreads();
    }
    if (t < 256) {
        int rowstart = base + pscan[t] - pv;
        int r = (b << 8) + t;
        if (r < NN) {
            rs[r] = rowstart;
            deg[r] = v;
            meta2[r] = make_int2(rowstart, v);
        }
        cur[t] = rowstart;
        for (int i = v; i < pv; ++i) col_s[rowstart + i] = NN;   // sentinel pads
    }
    __syncthreads();
    for (int i = base + t; i < end; i += 1024) {
        u32 p = pairs[i];
        int pos = atomicAdd(&cur[p >> 24], 1);
        col_s[pos] = (int)(p & 0x00FFFFFFu);
    }
}

// ---------------- t0 = dis ⊙ emb0, bf16 ----------------
__global__ void k_concat_t0(const float* __restrict__ u, const float* __restrict__ it,
                            const int* __restrict__ deg, u16* __restrict__ emb) {
    int i = blockIdx.x * blockDim.x + threadIdx.x;   // ushort4 index (4 dims), 16/row
    const int NU4 = NUSERS * DIM / 4;
    const int NT4 = NN * DIM / 4;
    if (i >= NT4) return;
    int row = i >> 4;
    int d = deg[row];
    float sc = (d > 0) ? (1.0f / sqrtf((float)d)) : 0.0f;
    float4 v = (i < NU4) ? ((const float4*)u)[i] : ((const float4*)it)[i - NU4];
    ushort4 o;
    o.x = f2bf(sc * v.x); o.y = f2bf(sc * v.y);
    o.z = f2bf(sc * v.z); o.w = f2bf(sc * v.w);
    ((ushort4*)emb)[i] = o;
}

// mark rows needed for hop-2 output: one wave per query row, lanes scatter
__global__ void k_mark(const int* __restrict__ uid, const int* __restrict__ iid,
                       const int* __restrict__ rs, const int* __restrict__ deg,
                       const int* __restrict__ col_s, unsigned char* __restrict__ m2) {
    int q = (blockIdx.x * blockDim.x + threadIdx.x) >> 6;
    if (q >= 2 * BQ) return;
    int lane = threadIdx.x & 63;
    int r = (q < BQ) ? uid[q] : (NUSERS + iid[q - BQ]);
    if (lane == 0) m2[r] = 1;
    int s = rs[r], n = deg[r];
    for (int i = lane; i < n; i += 64) m2[col_s[s + i]] = 1;
}

// hop-3 fused: one wave per query slot; out = (out + dis[r]*sum t2[c]) * 0.25
__global__ void __launch_bounds__(256) k_spmm_out(
        const int* __restrict__ rs, const int* __restrict__ deg,
        const int* __restrict__ col_s, const u16* __restrict__ in,
        const int* __restrict__ uid, const int* __restrict__ iid,
        float* __restrict__ out) {
    int q = (blockIdx.x * blockDim.x + threadIdx.x) >> 6;
    if (q >= 2 * BQ) return;
    int lane = threadIdx.x & 63;
    int eslot = lane >> 3;
    int dg = lane & 7;
    int dgoff = dg << 4;
    int b, r, off;
    if (q < BQ) { b = q; r = uid[q]; off = 0; }
    else { b = q - BQ; r = NUSERS + iid[q - BQ]; off = DIM; }
    int n = deg[r];
    int start = rs[r];
    int n8 = (n + 7) & ~7;
    const char* inb = (const char*)in;
    v2f acc2[4] = {(v2f)0.f, (v2f)0.f, (v2f)0.f, (v2f)0.f};
    if (n8 > 0)
        rowsum_core(start, n8, col_s, inb, eslot, dgoff, acc2);
    reduce_acc(acc2);
    if (eslot == 0) {
        float dr = (n > 0) ? (1.0f / sqrtf((float)n)) : 0.0f;   // dis[r]
        float* o = out + (size_t)b * (2 * DIM) + off + dg * 8;
#pragma unroll
        for (int j = 0; j < 4; ++j) {
            o[2 * j]     = (o[2 * j]     + dr * acc2[j].x) * 0.25f;
            o[2 * j + 1] = (o[2 * j + 1] + dr * acc2[j].y) * 0.25f;
        }
    }
}

// ---------------- output gathers ----------------

__global__ void k_gather_init(const int* __restrict__ uid, const int* __restrict__ iid,
                              const float* __restrict__ u, const float* __restrict__ it,
                              float* __restrict__ out) {
    int t = blockIdx.x * blockDim.x + threadIdx.x;
    if (t >= BQ * DIM) return;
    int b = t >> 6;
    int d = t & 63;
    out[b * (2 * DIM) + d]       = u[(size_t)uid[b] * DIM + d];
    out[b * (2 * DIM) + DIM + d] = it[(size_t)iid[b] * DIM + d];
}

// out += sqrt(deg[r]) * t_k[r]   (emb_k = rdis ⊙ t_k)
__global__ void k_gather_add(const int* __restrict__ uid, const int* __restrict__ iid,
                             const int* __restrict__ deg, const u16* __restrict__ emb,
                             float* __restrict__ out) {
    int t = blockIdx.x * blockDim.x + threadIdx.x;
    if (t >= BQ * DIM) return;
    int b = t >> 6;
    int d = t & 63;
    int ru = uid[b];
    int ri = NUSERS + iid[b];
    int du = deg[ru], di = deg[ri];
    float su = (du > 0) ? sqrtf((float)du) : 0.0f;
    float si = (di > 0) ? sqrtf((float)di) : 0.0f;
    int ou = b * (2 * DIM) + d;
    int oi = ou + DIM;
    out[ou] = out[ou] + su * bf2f(emb[(size_t)ru * DIM + d]);
    out[oi] = out[oi] + si * bf2f(emb[(size_t)ri * DIM + d]);
}

// ---------------- launch ----------------

extern "C" void kernel_launch(void* const* d_in, const int* in_sizes, int n_in,
                              void* d_out, int out_size, void* d_ws, size_t ws_size,
                              hipStream_t stream) {
    const float* users_emb = (const float*)d_in[0];
    const float* items_emb = (const float*)d_in[1];
    const int*   edge_row  = (const int*)d_in[2];
    const int*   edge_col  = (const int*)d_in[3];
    const int*   user_id   = (const int*)d_in[4];
    const int*   item_ids  = (const int*)d_in[5];
    float* out = (float*)d_out;

    char* ws = (char*)d_ws;
    // byte layout (ends ~90.3 MB):
    int*   deg_i   = (int*)  (ws + 0);          // 600 KB
    int*   rs      = (int*)  (ws + 655360);     // 600 KB
    int*   bin_cur = (int*)  (ws + 1310720);    // 2.4 KB
    unsigned char* m2 = (unsigned char*)(ws + 1400000);  // 150 KB
    int2*  meta2   = (int2*) (ws + 2097152);    // 1.2 MB
    int*   col_s   = (int*)  (ws + 4194304);    // 586*9216*4 = 21.6 MB
    u32*   pairs   = (u32*)  (ws + 29360128);   // 21.6 MB
    u16*   emb_a   = (u16*)  (ws + 54525952);   // (NN+1)*64*2 = 19.2 MB
    u16*   emb_b   = (u16*)  (ws + 75497472);   // 19.2 MB

    // init cursors + m2 + sentinel rows
    k_init<<<147, 256, 0, stream>>>(bin_cur, (u32*)m2, emb_a, emb_b);

    // binned CSR build (counting-sort pass A; pass B derives deg/rs/meta2)
    k_binA2<<<(NE + EPB2 - 1) / EPB2, 1024, 0, stream>>>(edge_row, edge_col, bin_cur,
                                                         pairs, NE);
    k_binB<<<NBIN, 1024, 0, stream>>>(pairs, bin_cur, col_s, rs, deg_i, meta2);

    // t0 table (bf16, dis-folded)
    k_concat_t0<<<(NN * DIM / 4 + 255) / 256, 256, 0, stream>>>(users_emb, items_emb,
                                                                deg_i, emb_a);

    // layer-0 contribution (fp32 sources)
    k_gather_init<<<(BQ * DIM + 255) / 256, 256, 0, stream>>>(user_id, item_ids,
                                                              users_emb, items_emb, out);

    // mark rows whose hop-2 output is read (one wave per query row)
    k_mark<<<(2 * BQ + 3) / 4, 256, 0, stream>>>(user_id, item_ids, rs, deg_i, col_s, m2);

    // hop 1: full (persistent 2-deep pipeline, 4096 waves x ~37 rows)
    k_spmm_p<false><<<1024, 256, 0, stream>>>(meta2, col_s, emb_a, emb_b,
                                              (const unsigned char*)nullptr);
    k_gather_add<<<(BQ * DIM + 255) / 256, 256, 0, stream>>>(user_id, item_ids, deg_i,
                                                             emb_b, out);
    // hop 2: masked
    k_spmm_p<true><<<1024, 256, 0, stream>>>(meta2, col_s, emb_b, emb_a, m2);
    k_gather_add<<<(BQ * DIM + 255) / 256, 256, 0, stream>>>(user_id, item_ids, deg_i,
                                                             emb_a, out);
    // hop 3: fused into output, fp32 accumulate, final /4
    k_spmm_out<<<(2 * BQ + 3) / 4, 256, 0, stream>>>(rs, deg_i, col_s, emb_a,
                                                     user_id, item_ids, out);
}

// Round 4
// 296.306 us; speedup vs baseline: 1.1539x; 1.1539x over previous
//
#include <hip/hip_runtime.h>
#include <hip/hip_bf16.h>

#define NUSERS 100000
#define NITEMS 50000
#define NN (NUSERS + NITEMS)      // 150000
#define NE 4000000
#define DIM 64
#define BQ 4096
#define NBIN ((NN + 255) >> 8)    // 586 bins of 256 rows
#define BINCAP 9216               // fixed slots/bin; mean w/ pads 7851, sigma ~90
#define EPB2 8192                 // edges per block in pass A (8/thread @ 1024)

typedef unsigned short u16;
typedef unsigned int u32;
typedef float v2f __attribute__((ext_vector_type(2)));
typedef unsigned u32x2 __attribute__((ext_vector_type(2)));

__device__ __forceinline__ float bf2f(u16 u) {
    return __uint_as_float(((unsigned)u) << 16);
}
__device__ __forceinline__ u16 f2bf(float f) {
    unsigned x = __float_as_uint(f);
    return (u16)((x + 0x7FFFu + ((x >> 16) & 1u)) >> 16);   // RNE
}
// unpack uint4 (8 bf16) into 4 packed-f32 accumulates (v_pk_add_f32)
__device__ __forceinline__ void add8p(v2f* acc2, uint4 u) {
    acc2[0] += (v2f){__uint_as_float(u.x << 16), __uint_as_float(u.x & 0xffff0000u)};
    acc2[1] += (v2f){__uint_as_float(u.y << 16), __uint_as_float(u.y & 0xffff0000u)};
    acc2[2] += (v2f){__uint_as_float(u.z << 16), __uint_as_float(u.z & 0xffff0000u)};
    acc2[3] += (v2f){__uint_as_float(u.w << 16), __uint_as_float(u.w & 0xffff0000u)};
}

// ---- cross-lane adds on the VALU pipe (no ds/lgkm chains) ----
// xadd8: sum over lane bit 3 (row_ror:8 within 16-lane DPP rows)
#if __has_builtin(__builtin_amdgcn_update_dpp)
__device__ __forceinline__ float xadd8(float x) {
    int y = __builtin_amdgcn_update_dpp(0, __float_as_int(x), 0x128, 0xF, 0xF, true);
    return x + __int_as_float(y);
}
#else
__device__ __forceinline__ float xadd8(float x) { return x + __shfl_xor(x, 8, 64); }
#endif
// xadd16: sum over lane bit 4 (stays within each 32-lane half)
#if __has_builtin(__builtin_amdgcn_permlane16_swap)
__device__ __forceinline__ float xadd16(float x) {
    u32x2 r = __builtin_amdgcn_permlane16_swap(__float_as_uint(x), __float_as_uint(x),
                                               false, false);
    return __uint_as_float(r.x) + __uint_as_float(r.y);
}
#else
__device__ __forceinline__ float xadd16(float x) { return x + __shfl_xor(x, 16, 64); }
#endif

#if __has_builtin(__builtin_amdgcn_sched_barrier)
#define SCHED_FENCE() __builtin_amdgcn_sched_barrier(0)
#else
#define SCHED_FENCE()
#endif

// reduce over the 4 edge slots of each 32-lane half (lane bits 3,4)
__device__ __forceinline__ void reduce_half(v2f* acc2) {
#pragma unroll
    for (int j = 0; j < 4; ++j) { acc2[j].x = xadd8(acc2[j].x);  acc2[j].y = xadd8(acc2[j].y);  }
#pragma unroll
    for (int j = 0; j < 4; ++j) { acc2[j].x = xadd16(acc2[j].x); acc2[j].y = xadd16(acc2[j].y); }
}

// one batch of 8 gathers covering slots [s0, s0+32) of this half's row;
// invalid slots -> sentinel row NN (zeros, L1-hot)
__device__ __forceinline__ void batch8(const int* __restrict__ col_s, int start,
                                       int s0, int lim, int eslot,
                                       const char* __restrict__ base2, v2f* acc2) {
    int cg[8];
#pragma unroll
    for (int g = 0; g < 8; ++g) {
        int slot = s0 + (g << 2) + eslot;
        int c = col_s[start + slot];
        cg[g] = (slot < lim) ? c : NN;
    }
    uint4 v[8];
#pragma unroll
    for (int g = 0; g < 8; ++g)
        v[g] = *(const uint4*)(base2 + (((u32)cg[g]) << 7));
    SCHED_FENCE();
#pragma unroll
    for (int g = 0; g < 8; ++g) add8p(acc2, v[g]);
}

// ---------------- SpMM: 2 rows per wave, 32 lanes (4 eslots x 8 dg) per row ----
// t_{k+1}[r] = (1/deg[r]) * sum_{c in N(r)} t_k[c]
template<bool MASKED>
__global__ void __launch_bounds__(256) k_spmm2(
        const int2* __restrict__ meta2, const int* __restrict__ col_s,
        const u16* __restrict__ in, u16* __restrict__ out,
        const unsigned char* __restrict__ mask) {
    int wid = (blockIdx.x * blockDim.x + threadIdx.x) >> 6;
    int lane = threadIdx.x & 63;
    int half = lane >> 5;
    int eslot = (lane >> 3) & 3;
    int dg = lane & 7;
    int r = (wid << 1) + half;            // grid sized so r < NN always
    int2 mv = meta2[r];
    int start = mv.x, n = mv.y;
    int m = MASKED ? (int)mask[r] : 1;
    int n8 = (n + 7) & ~7;
    int lim = m ? n8 : 0;
    if (MASKED && !__any(lim > 0)) return;
    const char* base2 = (const char*)in + (dg << 4);

    v2f acc2[4] = {(v2f)0.f, (v2f)0.f, (v2f)0.f, (v2f)0.f};
    batch8(col_s, start, 0, lim, eslot, base2, acc2);
    if (__any(lim > 32))
        batch8(col_s, start, 32, lim, eslot, base2, acc2);
    if (__any(lim > 64)) {                // safety net; ~never with this input
        for (int i = 64 + eslot; i < lim; i += 4) {
            int c = col_s[start + i];
            uint4 u = *(const uint4*)(base2 + (((u32)c) << 7));
            add8p(acc2, u);
        }
    }
    reduce_half(acc2);
    if (eslot == 0 && m) {
        float sc = (n > 0) ? (1.0f / (float)n) : 0.0f;   // dis[r]^2
        v2f vs = {sc, sc};
        u32 p[4];
#pragma unroll
        for (int j = 0; j < 4; ++j) {
            v2f t = acc2[j] * vs;
            __hip_bfloat162 h = __float22bfloat162_rn(make_float2(t.x, t.y));
            p[j] = *(u32*)&h;
        }
        ((uint4*)out)[(size_t)r * 8 + dg] = make_uint4(p[0], p[1], p[2], p[3]);
    }
}

// hop-3 fused: 2 query slots per wave; out = (out + dis[r]*sum t2[c]) * 0.25
__global__ void __launch_bounds__(256) k_spmm_out2(
        const int2* __restrict__ meta2, const int* __restrict__ col_s,
        const u16* __restrict__ in, const int* __restrict__ uid,
        const int* __restrict__ iid, float* __restrict__ out) {
    int wid = (blockIdx.x * blockDim.x + threadIdx.x) >> 6;
    int lane = threadIdx.x & 63;
    int half = lane >> 5;
    int eslot = (lane >> 3) & 3;
    int dg = lane & 7;
    int q = (wid << 1) + half;            // grid sized so q < 2*BQ always
    int b, r, off;
    if (q < BQ) { b = q; r = uid[q]; off = 0; }
    else { b = q - BQ; r = NUSERS + iid[q - BQ]; off = DIM; }
    int2 mv = meta2[r];
    int start = mv.x, n = mv.y;
    int n8 = (n + 7) & ~7;
    const char* base2 = (const char*)in + (dg << 4);

    v2f acc2[4] = {(v2f)0.f, (v2f)0.f, (v2f)0.f, (v2f)0.f};
    batch8(col_s, start, 0, n8, eslot, base2, acc2);
    if (__any(n8 > 32))
        batch8(col_s, start, 32, n8, eslot, base2, acc2);
    if (__any(n8 > 64)) {
        for (int i = 64 + eslot; i < n8; i += 4) {
            int c = col_s[start + i];
            uint4 u = *(const uint4*)(base2 + (((u32)c) << 7));
            add8p(acc2, u);
        }
    }
    reduce_half(acc2);
    if (eslot == 0) {
        float dr = (n > 0) ? (1.0f / sqrtf((float)n)) : 0.0f;   // dis[r]
        float* o = out + (size_t)b * (2 * DIM) + off + dg * 8;
#pragma unroll
        for (int j = 0; j < 4; ++j) {
            o[2 * j]     = (o[2 * j]     + dr * acc2[j].x) * 0.25f;
            o[2 * j + 1] = (o[2 * j + 1] + dr * acc2[j].y) * 0.25f;
        }
    }
}

// ---------------- init: bin cursors, m2 mask, sentinel rows ----------------
__global__ void k_init(int* __restrict__ bin_cur, u32* __restrict__ m2w,
                       u16* __restrict__ ea, u16* __restrict__ eb) {
    int t = blockIdx.x * blockDim.x + threadIdx.x;
    if (t < NBIN) bin_cur[t] = t * BINCAP;
    if (t < 37504) m2w[t] = 0;                 // zero 150016 bytes of m2
    if (t < 32) {                              // zero sentinel row NN in both tables
        ((u32*)(ea + (size_t)NN * DIM))[t] = 0;
        ((u32*)(eb + (size_t)NN * DIM))[t] = 0;
    }
}

// ---------------- Pass A: block-local counting sort, coalesced flush -------
__global__ void __launch_bounds__(1024) k_binA2(
        const int* __restrict__ row, const int* __restrict__ col,
        int* __restrict__ bin_cur, u32* __restrict__ pairs, int E) {
    __shared__ u32 stage[EPB2];            // 32 KB
    __shared__ int hist[NBIN];
    __shared__ int base_l[NBIN];
    __shared__ int cbase[NBIN];
    __shared__ int lcur[NBIN];
    __shared__ int s[1024];
    int t = threadIdx.x;
    int base = blockIdx.x * EPB2;
    int lim = min(E - base, EPB2);

    if (t < NBIN) hist[t] = 0;
    __syncthreads();

    for (int i = t; i < lim; i += 1024)
        atomicAdd(&hist[row[base + i] >> 8], 1);
    __syncthreads();

    int v = (t < NBIN) ? hist[t] : 0;
    s[t] = v;
    __syncthreads();
    for (int off = 1; off < 1024; off <<= 1) {
        int x = (t >= off) ? s[t - off] : 0;
        __syncthreads();
        s[t] += x;
        __syncthreads();
    }
    if (t < NBIN) {
        int excl = s[t] - v;
        base_l[t] = excl;
        lcur[t] = excl;
        cbase[t] = (v > 0) ? atomicAdd(&bin_cur[t], v) : 0;
    }
    __syncthreads();

    for (int i = t; i < lim; i += 1024) {
        int r = row[base + i];
        int c = col[base + i];
        int pos = atomicAdd(&lcur[r >> 8], 1);
        stage[pos] = ((u32)(r & 255) << 24) | (u32)c;
    }
    __syncthreads();

    int wv = t >> 6;
    int lane = t & 63;
    for (int b = wv; b < NBIN; b += 16) {
        int h = hist[b];
        int lb = base_l[b];
        size_t gb = (size_t)cbase[b];
        for (int i = lane; i < h; i += 64)
            pairs[gb + i] = stage[lb + i];
    }
}

// ---------------- Pass B: per-bin row sort; derives rs/deg/meta2; pads to 8 ----
__global__ void __launch_bounds__(1024) k_binB(
        const u32* __restrict__ pairs, const int* __restrict__ bin_cur,
        int* __restrict__ col_s, int* __restrict__ rs, int* __restrict__ deg,
        int2* __restrict__ meta2) {
    __shared__ int cnt[256];
    __shared__ int pscan[256];
    __shared__ int cur[256];
    int b = blockIdx.x;
    int t = threadIdx.x;
    int base = b * BINCAP;
    int end = bin_cur[b];
    if (t < 256) cnt[t] = 0;
    __syncthreads();
    for (int i = base + t; i < end; i += 1024)
        atomicAdd(&cnt[pairs[i] >> 24], 1);
    __syncthreads();
    int v = (t < 256) ? cnt[t] : 0;
    int pv = (v + 7) & ~7;                    // row segment padded to multiple of 8
    if (t < 256) pscan[t] = pv;
    __syncthreads();
    for (int off = 1; off < 256; off <<= 1) {
        int x = (t >= off && t < 256) ? pscan[t - off] : 0;
        __syncthreads();
        if (t < 256) pscan[t] += x;
        __syncthreads();
    }
    if (t < 256) {
        int rowstart = base + pscan[t] - pv;
        int r = (b << 8) + t;
        if (r < NN) {
            rs[r] = rowstart;
            deg[r] = v;
            meta2[r] = make_int2(rowstart, v);
        }
        cur[t] = rowstart;
        for (int i = v; i < pv; ++i) col_s[rowstart + i] = NN;   // sentinel pads
    }
    __syncthreads();
    for (int i = base + t; i < end; i += 1024) {
        u32 p = pairs[i];
        int pos = atomicAdd(&cur[p >> 24], 1);
        col_s[pos] = (int)(p & 0x00FFFFFFu);
    }
}

// ---------------- t0 = dis ⊙ emb0, bf16 ----------------
__global__ void k_concat_t0(const float* __restrict__ u, const float* __restrict__ it,
                            const int* __restrict__ deg, u16* __restrict__ emb) {
    int i = blockIdx.x * blockDim.x + threadIdx.x;   // ushort4 index (4 dims), 16/row
    const int NU4 = NUSERS * DIM / 4;
    const int NT4 = NN * DIM / 4;
    if (i >= NT4) return;
    int row = i >> 4;
    int d = deg[row];
    float sc = (d > 0) ? (1.0f / sqrtf((float)d)) : 0.0f;
    float4 v = (i < NU4) ? ((const float4*)u)[i] : ((const float4*)it)[i - NU4];
    ushort4 o;
    o.x = f2bf(sc * v.x); o.y = f2bf(sc * v.y);
    o.z = f2bf(sc * v.z); o.w = f2bf(sc * v.w);
    ((ushort4*)emb)[i] = o;
}

// mark rows needed for hop-2 output: one wave per query row, lanes scatter
__global__ void k_mark(const int* __restrict__ uid, const int* __restrict__ iid,
                       const int* __restrict__ rs, const int* __restrict__ deg,
                       const int* __restrict__ col_s, unsigned char* __restrict__ m2) {
    int q = (blockIdx.x * blockDim.x + threadIdx.x) >> 6;
    if (q >= 2 * BQ) return;
    int lane = threadIdx.x & 63;
    int r = (q < BQ) ? uid[q] : (NUSERS + iid[q - BQ]);
    if (lane == 0) m2[r] = 1;
    int s = rs[r], n = deg[r];
    for (int i = lane; i < n; i += 64) m2[col_s[s + i]] = 1;
}

// ---------------- output gathers ----------------

__global__ void k_gather_init(const int* __restrict__ uid, const int* __restrict__ iid,
                              const float* __restrict__ u, const float* __restrict__ it,
                              float* __restrict__ out) {
    int t = blockIdx.x * blockDim.x + threadIdx.x;
    if (t >= BQ * DIM) return;
    int b = t >> 6;
    int d = t & 63;
    out[b * (2 * DIM) + d]       = u[(size_t)uid[b] * DIM + d];
    out[b * (2 * DIM) + DIM + d] = it[(size_t)iid[b] * DIM + d];
}

// out += sqrt(deg[r]) * t_k[r]   (emb_k = rdis ⊙ t_k)
__global__ void k_gather_add(const int* __restrict__ uid, const int* __restrict__ iid,
                             const int* __restrict__ deg, const u16* __restrict__ emb,
                             float* __restrict__ out) {
    int t = blockIdx.x * blockDim.x + threadIdx.x;
    if (t >= BQ * DIM) return;
    int b = t >> 6;
    int d = t & 63;
    int ru = uid[b];
    int ri = NUSERS + iid[b];
    int du = deg[ru], di = deg[ri];
    float su = (du > 0) ? sqrtf((float)du) : 0.0f;
    float si = (di > 0) ? sqrtf((float)di) : 0.0f;
    int ou = b * (2 * DIM) + d;
    int oi = ou + DIM;
    out[ou] = out[ou] + su * bf2f(emb[(size_t)ru * DIM + d]);
    out[oi] = out[oi] + si * bf2f(emb[(size_t)ri * DIM + d]);
}

// ---------------- launch ----------------

extern "C" void kernel_launch(void* const* d_in, const int* in_sizes, int n_in,
                              void* d_out, int out_size, void* d_ws, size_t ws_size,
                              hipStream_t stream) {
    const float* users_emb = (const float*)d_in[0];
    const float* items_emb = (const float*)d_in[1];
    const int*   edge_row  = (const int*)d_in[2];
    const int*   edge_col  = (const int*)d_in[3];
    const int*   user_id   = (const int*)d_in[4];
    const int*   item_ids  = (const int*)d_in[5];
    float* out = (float*)d_out;

    char* ws = (char*)d_ws;
    // byte layout (ends ~90.3 MB):
    int*   deg_i   = (int*)  (ws + 0);          // 600 KB
    int*   rs      = (int*)  (ws + 655360);     // 600 KB
    int*   bin_cur = (int*)  (ws + 1310720);    // 2.4 KB
    unsigned char* m2 = (unsigned char*)(ws + 1400000);  // 150 KB
    int2*  meta2   = (int2*) (ws + 2097152);    // 1.2 MB
    int*   col_s   = (int*)  (ws + 4194304);    // 586*9216*4 = 21.6 MB
    u32*   pairs   = (u32*)  (ws + 29360128);   // 21.6 MB
    u16*   emb_a   = (u16*)  (ws + 54525952);   // (NN+1)*64*2 = 19.2 MB
    u16*   emb_b   = (u16*)  (ws + 75497472);   // 19.2 MB

    // init cursors + m2 + sentinel rows
    k_init<<<147, 256, 0, stream>>>(bin_cur, (u32*)m2, emb_a, emb_b);

    // binned CSR build (counting-sort pass A; pass B derives deg/rs/meta2)
    k_binA2<<<(NE + EPB2 - 1) / EPB2, 1024, 0, stream>>>(edge_row, edge_col, bin_cur,
                                                         pairs, NE);
    k_binB<<<NBIN, 1024, 0, stream>>>(pairs, bin_cur, col_s, rs, deg_i, meta2);

    // t0 table (bf16, dis-folded)
    k_concat_t0<<<(NN * DIM / 4 + 255) / 256, 256, 0, stream>>>(users_emb, items_emb,
                                                                deg_i, emb_a);

    // layer-0 contribution (fp32 sources)
    k_gather_init<<<(BQ * DIM + 255) / 256, 256, 0, stream>>>(user_id, item_ids,
                                                              users_emb, items_emb, out);

    // mark rows whose hop-2 output is read (one wave per query row)
    k_mark<<<(2 * BQ + 3) / 4, 256, 0, stream>>>(user_id, item_ids, rs, deg_i, col_s, m2);

    // hops: 2 rows per wave, 4 waves per block -> NN/2/4 = 18750 blocks exactly
    // hop 1: full
    k_spmm2<false><<<18750, 256, 0, stream>>>(meta2, col_s, emb_a, emb_b,
                                              (const unsigned char*)nullptr);
    k_gather_add<<<(BQ * DIM + 255) / 256, 256, 0, stream>>>(user_id, item_ids, deg_i,
                                                             emb_b, out);
    // hop 2: masked
    k_spmm2<true><<<18750, 256, 0, stream>>>(meta2, col_s, emb_b, emb_a, m2);
    k_gather_add<<<(BQ * DIM + 255) / 256, 256, 0, stream>>>(user_id, item_ids, deg_i,
                                                             emb_a, out);
    // hop 3: fused into output, fp32 accumulate, final /4 (2*BQ/2/4 = 1024 blocks)
    k_spmm_out2<<<1024, 256, 0, stream>>>(meta2, col_s, emb_a, user_id, item_ids, out);
}